// Round 2
// baseline (21427.000 us; speedup 1.0000x reference)
//
#include <hip/hip_runtime.h>

typedef __attribute__((ext_vector_type(8))) short bf16frag;
typedef __attribute__((ext_vector_type(4))) float f32x4;

constexpr int B = 128, S = 1024, DI = 256, DH = 512, DO = 256;
constexpr int NBUF = 4;
constexpr size_t OUT_MAIN = (size_t)B * S * DO;           // 33554432 elements
constexpr size_t HBUF_BYTES = (size_t)NBUF * B * DH * 2;  // 524288
constexpr size_t FLAGS_BYTES = 8 * 64 * 4;                // 2048
// LDS layout (ushort offsets)
constexpr int WH_OFF = 0;        // 32 rows * 512
constexpr int WX_OFF = 16384;    // 32 rows * 256
constexpr int WHO_OFF = 24576;   // 16 rows * 512
constexpr int LDS_BYTES = 65536;

__device__ __forceinline__ unsigned short f2bf(float f) {
  unsigned int u = __float_as_uint(f);
  u += 0x7fffu + ((u >> 16) & 1u);          // RNE
  return (unsigned short)(u >> 16);
}
__device__ __forceinline__ float bf2f(unsigned short h) {
  return __uint_as_float(((unsigned int)h) << 16);
}
__device__ __forceinline__ float fast_tanh(float x) {
  float e = __expf(2.0f * x);               // inf-safe: e=inf -> 1 ; e=0 -> -1
  return 1.0f - 2.0f * __builtin_amdgcn_rcpf(e + 1.0f);
}
__device__ __forceinline__ bf16frag cvt8(float4 a, float4 b) {
  bf16frag r;
  r[0]=(short)f2bf(a.x); r[1]=(short)f2bf(a.y); r[2]=(short)f2bf(a.z); r[3]=(short)f2bf(a.w);
  r[4]=(short)f2bf(b.x); r[5]=(short)f2bf(b.y); r[6]=(short)f2bf(b.z); r[7]=(short)f2bf(b.w);
  return r;
}
// 8 consecutive elements at element-offset `off` (off % 8 == 0) -> bf16 frag
__device__ __forceinline__ bf16frag load8(const void* base, size_t off, bool fp32m) {
  if (fp32m) {
    const float4* p = reinterpret_cast<const float4*>((const float*)base + off);
    return cvt8(p[0], p[1]);
  }
  return *reinterpret_cast<const bf16frag*>((const unsigned short*)base + off);
}

// Wait until all 32 w0/w1 flags >= T1 and all 16 w2 flags >= T2. Bounded spin.
__device__ __forceinline__ void cluster_wait(const int* f01, const int* f2, int T1, int T2) {
  const int lane = threadIdx.x & 63;
  const int* addr;
  int thr;
  if (lane < 32)      { addr = f01 + lane;        thr = T1; }
  else if (lane < 48) { addr = f2 + (lane - 32);  thr = T2; }
  else                { addr = f01;               thr = (int)0x80000000; }
  int guard = 0;
  while (true) {
    int v = __hip_atomic_load(addr, __ATOMIC_RELAXED, __HIP_MEMORY_SCOPE_AGENT);
    if (__all(v >= thr)) break;
    if (++guard > (1 << 26)) break;       // terminate instead of hang on protocol bug
    __builtin_amdgcn_s_sleep(1);
  }
}

__global__ void __launch_bounds__(192, 1)
rnn_persistent(const void* __restrict__ xv,
               const void* __restrict__ Wi2hv,
               const void* __restrict__ biv,
               const void* __restrict__ Whov,
               const void* __restrict__ bov,
               void* __restrict__ outv,
               unsigned short* __restrict__ hbuf,
               int* __restrict__ flags) {
  extern __shared__ unsigned short lds[];
  const int tid = threadIdx.x;
  const int lane = tid & 63;
  const int wave = tid >> 6;     // 0,1: recurrence tiles; 2: output GEMM
  const int blk = blockIdx.x;
  const int c   = blk & 7;       // cluster (batch slice), %8 -> XCD-local heuristic
  const int mem = blk >> 3;      // member 0..15 (hidden/out slice)
  const int b0  = c * 16;
  const int n_base = mem * 32;
  const int o_base = mem * 16;

  // ---- dtype detection: fp32 data read as ushorts has ~25% "huge exponent"
  // patterns in the mantissa halves; genuine bf16 N(0,1) has none. Wave-local
  // scan of the same 4096 ushorts -> identical, block-uniform verdict.
  bool fp32m;
  {
    const unsigned short* xu = (const unsigned short*)xv;
    int c0 = 0;
    for (int i = lane; i < 4096; i += 64)
      c0 += (((xu[i] >> 7) & 0xFF) >= 0xC0);
    #pragma unroll
    for (int s = 32; s; s >>= 1) c0 += __shfl_xor(c0, s, 64);
    fp32m = (c0 > 100);
  }

  // ---- stage weight slices into LDS (always bf16), 16B-block XOR swizzle ----
  for (int i = tid; i < 32 * 64; i += 192) {              // Wh slice: 32 x 512
    int r = i >> 6, bk = i & 63;
    bf16frag v = load8(Wi2hv, (size_t)(n_base + r) * 768 + 256 + bk * 8, fp32m);
    *reinterpret_cast<bf16frag*>(lds + WH_OFF + r * 512 + ((bk ^ (r & 7)) * 8)) = v;
  }
  for (int i = tid; i < 32 * 32; i += 192) {              // Wx slice: 32 x 256
    int r = i >> 5, bk = i & 31;
    bf16frag v = load8(Wi2hv, (size_t)(n_base + r) * 768 + bk * 8, fp32m);
    *reinterpret_cast<bf16frag*>(lds + WX_OFF + r * 256 + ((bk ^ (r & 7)) * 8)) = v;
  }
  for (int i = tid; i < 16 * 64; i += 192) {              // Who slice: 16 x 512
    int r = i >> 6, bk = i & 63;
    bf16frag v = load8(Whov, (size_t)(o_base + r) * 512 + bk * 8, fp32m);
    *reinterpret_cast<bf16frag*>(lds + WHO_OFF + r * 512 + ((bk ^ (r & 7)) * 8)) = v;
  }
  __syncthreads();

  int* f01 = flags + c * 64;
  int* f2  = f01 + 32;
  const int q  = lane >> 4;
  const int ln = lane & 15;
  float* outf = (float*)outv;
  unsigned short* outh = (unsigned short*)outv;

  if (wave < 2) {
    const int nlB  = wave * 16 + ln;        // local B-frag row in Wh/Wx LDS
    const int n_g  = n_base + nlB;          // global hidden index (bias / store col)
    const float bias = fp32m ? ((const float*)biv)[n_g]
                             : bf2f(((const unsigned short*)biv)[n_g]);
    const int swz = nlB & 7;
    const size_t xrow = (size_t)(b0 + ln) * (S * DI) + q * 8;
    const int flag_idx = mem * 2 + wave;
    const size_t hrow_off = (size_t)(b0 + ln) * DH + q * 8;

    bf16frag xf[8];
    #pragma unroll
    for (int cc = 0; cc < 8; ++cc)
      xf[cc] = load8(xv, xrow + cc * 32, fp32m);

    for (int t = 0; t < S; ++t) {
      f32x4 acc = {bias, bias, bias, bias};
      // x-part: independent of h, runs before the wait (latency hidden in sync)
      #pragma unroll
      for (int cc = 0; cc < 8; ++cc) {
        bf16frag wf = *reinterpret_cast<const bf16frag*>(
            lds + WX_OFF + nlB * 256 + (((cc * 4 + q) ^ swz) * 8));
        acc = __builtin_amdgcn_mfma_f32_16x16x32_bf16(xf[cc], wf, acc, 0, 0, 0);
      }
      if (t + 1 < S) {  // prefetch next step's x; stays in flight across the wait
        #pragma unroll
        for (int cc = 0; cc < 8; ++cc)
          xf[cc] = load8(xv, xrow + (size_t)(t + 1) * DI + cc * 32, fp32m);
      }
      if (t > 0) {
        // flags01 >= t : h_{t-1} fully posted. flags2 >= t-3 : wave2 done with
        // h_{t-4} (which hbuf[t&3] is about to overwrite). 4-deep ring => safe.
        cluster_wait(f01, f2, t, t - 3);
        __threadfence();
        const unsigned short* hsrc = hbuf + (size_t)((t - 1) & 3) * (B * DH) + hrow_off;
        unsigned long long hlo[16], hhi[16];
        #pragma unroll
        for (int cc = 0; cc < 16; ++cc) {
          const unsigned long long* p = reinterpret_cast<const unsigned long long*>(hsrc + cc * 32);
          hlo[cc] = __hip_atomic_load(p,     __ATOMIC_RELAXED, __HIP_MEMORY_SCOPE_AGENT);
          hhi[cc] = __hip_atomic_load(p + 1, __ATOMIC_RELAXED, __HIP_MEMORY_SCOPE_AGENT);
        }
        #pragma unroll
        for (int cc = 0; cc < 16; ++cc) {
          union { unsigned long long u[2]; bf16frag f; } cvt;
          cvt.u[0] = hlo[cc]; cvt.u[1] = hhi[cc];
          bf16frag wf = *reinterpret_cast<const bf16frag*>(
              lds + WH_OFF + nlB * 512 + (((cc * 4 + q) ^ swz) * 8));
          acc = __builtin_amdgcn_mfma_f32_16x16x32_bf16(cvt.f, wf, acc, 0, 0, 0);
        }
      }
      unsigned short* hdst = hbuf + (size_t)(t & 3) * (B * DH);
      #pragma unroll
      for (int r = 0; r < 4; ++r) {
        float hv = fast_tanh(acc[r]);
        unsigned short hu = f2bf(hv);
        // pack col pairs across adjacent lanes -> one coherent 32-bit store
        unsigned int other = __shfl_xor((unsigned int)hu, 1, 64);
        if ((lane & 1) == 0) {
          unsigned int packed = (unsigned int)hu | (other << 16);
          __hip_atomic_store(reinterpret_cast<unsigned int*>(
              hdst + (size_t)(b0 + q * 4 + r) * DH + n_g),
              packed, __ATOMIC_RELAXED, __HIP_MEMORY_SCOPE_AGENT);
        }
        if (t == S - 1) {
          size_t hidx = OUT_MAIN + (size_t)(b0 + q * 4 + r) * DH + n_g;
          if (fp32m) outf[hidx] = hv; else outh[hidx] = hu;   // h_last
        }
      }
      __threadfence();  // release: h stores visible before flag
      if (lane == 0)
        __hip_atomic_store(f01 + flag_idx, t + 1, __ATOMIC_RELAXED, __HIP_MEMORY_SCOPE_AGENT);
    }
  } else {
    // wave2: out_u = h_u @ Who^T + b, trails the recurrence by design
    const int o_g = o_base + ln;
    const float bias = fp32m ? ((const float*)bov)[o_g]
                             : bf2f(((const unsigned short*)bov)[o_g]);
    const int swz = ln & 7;
    const size_t hrow_off = (size_t)(b0 + ln) * DH + q * 8;
    for (int u = 0; u < S; ++u) {
      cluster_wait(f01, f2, u + 1, (int)0x80000000);
      __threadfence();
      const unsigned short* hsrc = hbuf + (size_t)(u & 3) * (B * DH) + hrow_off;
      unsigned long long hlo[16], hhi[16];
      #pragma unroll
      for (int cc = 0; cc < 16; ++cc) {
        const unsigned long long* p = reinterpret_cast<const unsigned long long*>(hsrc + cc * 32);
        hlo[cc] = __hip_atomic_load(p,     __ATOMIC_RELAXED, __HIP_MEMORY_SCOPE_AGENT);
        hhi[cc] = __hip_atomic_load(p + 1, __ATOMIC_RELAXED, __HIP_MEMORY_SCOPE_AGENT);
      }
      f32x4 acc = {bias, bias, bias, bias};
      #pragma unroll
      for (int cc = 0; cc < 16; ++cc) {
        union { unsigned long long u[2]; bf16frag f; } cvt;
        cvt.u[0] = hlo[cc]; cvt.u[1] = hhi[cc];
        bf16frag wf = *reinterpret_cast<const bf16frag*>(
            lds + WHO_OFF + ln * 512 + (((cc * 4 + q) ^ swz) * 8));
        acc = __builtin_amdgcn_mfma_f32_16x16x32_bf16(cvt.f, wf, acc, 0, 0, 0);
      }
      #pragma unroll
      for (int r = 0; r < 4; ++r) {
        size_t oidx = ((size_t)(b0 + q * 4 + r) * S + u) * DO + o_g;
        if (fp32m) outf[oidx] = acc[r]; else outh[oidx] = f2bf(acc[r]);
      }
      __threadfence();  // h_u loads complete before signaling buffer reusable
      if (lane == 0)
        __hip_atomic_store(f2 + mem, u + 1, __ATOMIC_RELAXED, __HIP_MEMORY_SCOPE_AGENT);
    }
  }
}

extern "C" void kernel_launch(void* const* d_in, const int* in_sizes, int n_in,
                              void* d_out, int out_size, void* d_ws, size_t ws_size,
                              hipStream_t stream) {
  const void* x    = d_in[0];
  const void* Wi2h = d_in[1];
  const void* bi   = d_in[2];
  const void* Who  = d_in[3];
  const void* bo   = d_in[4];
  void* out = d_out;
  unsigned short* hbuf = (unsigned short*)d_ws;
  int* flags = (int*)((char*)d_ws + HBUF_BYTES);
  if (ws_size < HBUF_BYTES + FLAGS_BYTES) return;  // loud failure over corruption

  hipMemsetAsync(flags, 0, FLAGS_BYTES, stream);   // monotonic flags start at 0

  void* args[] = { (void*)&x, (void*)&Wi2h, (void*)&bi, (void*)&Who, (void*)&bo,
                   (void*)&out, (void*)&hbuf, (void*)&flags };
  hipError_t e = hipLaunchCooperativeKernel((void*)rnn_persistent, dim3(128), dim3(192),
                                            args, LDS_BYTES, stream);
  if (e != hipSuccess) {
    // co-residency fallback: 128 blocks <= 256 CUs, all resident on dispatch
    rnn_persistent<<<dim3(128), dim3(192), LDS_BYTES, stream>>>(
        x, Wi2h, bi, Who, bo, out, hbuf, flags);
  }
}

// Round 3
// 8538.224 us; speedup vs baseline: 2.5095x; 2.5095x over previous
//
#include <hip/hip_runtime.h>

typedef __attribute__((ext_vector_type(8))) short bf16frag;
typedef __attribute__((ext_vector_type(4))) float f32x4;

constexpr int B = 128, S = 1024, DI = 256, DH = 512, DO = 256;
constexpr int NBUF = 4;
constexpr size_t OUT_MAIN = (size_t)B * S * DO;           // 33554432 elements
constexpr size_t HBUF_BYTES = (size_t)NBUF * B * DH * 2;  // 524288
constexpr size_t FLAGS_BYTES = 8 * 64 * 4;                // 2048
// LDS layout (ushort offsets)
constexpr int WH_OFF = 0;        // 32 rows * 512
constexpr int WX_OFF = 16384;    // 32 rows * 256
constexpr int WHO_OFF = 24576;   // 16 rows * 512
constexpr int LDS_BYTES = 65536;

// Release: all prior sc1 (MALL-direct) stores acked before anything after.
// NOT __threadfence(): that emits buffer_wbl2/buffer_inv (whole-L2 flush) on
// gfx950 — measured 21 us/step with it; our cross-block data is atomic-only
// (L2-bypassing), so vmcnt(0) alone is the correct, minimal release.
__device__ __forceinline__ void release_vm() {
  asm volatile("s_waitcnt vmcnt(0)" ::: "memory");
}
__device__ __forceinline__ void acquire_cc() {
  asm volatile("" ::: "memory");   // compiler barrier; MALL loads need no inv
}

__device__ __forceinline__ unsigned short f2bf(float f) {
  unsigned int u = __float_as_uint(f);
  u += 0x7fffu + ((u >> 16) & 1u);          // RNE
  return (unsigned short)(u >> 16);
}
__device__ __forceinline__ float bf2f(unsigned short h) {
  return __uint_as_float(((unsigned int)h) << 16);
}
__device__ __forceinline__ float fast_tanh(float x) {
  float e = __expf(2.0f * x);               // inf-safe: e=inf -> 1 ; e=0 -> -1
  return 1.0f - 2.0f * __builtin_amdgcn_rcpf(e + 1.0f);
}
__device__ __forceinline__ bf16frag cvt8(float4 a, float4 b) {
  bf16frag r;
  r[0]=(short)f2bf(a.x); r[1]=(short)f2bf(a.y); r[2]=(short)f2bf(a.z); r[3]=(short)f2bf(a.w);
  r[4]=(short)f2bf(b.x); r[5]=(short)f2bf(b.y); r[6]=(short)f2bf(b.z); r[7]=(short)f2bf(b.w);
  return r;
}
// 8 consecutive elements at element-offset `off` (off % 8 == 0) -> bf16 frag
__device__ __forceinline__ bf16frag load8(const void* base, size_t off, bool fp32m) {
  if (fp32m) {
    const float4* p = reinterpret_cast<const float4*>((const float*)base + off);
    return cvt8(p[0], p[1]);
  }
  return *reinterpret_cast<const bf16frag*>((const unsigned short*)base + off);
}

// Wait until all 32 w0/w1 flags >= T1 and all 16 w2 flags >= T2. Bounded spin.
__device__ __forceinline__ void cluster_wait(const int* f01, const int* f2, int T1, int T2) {
  const int lane = threadIdx.x & 63;
  const int* addr;
  int thr;
  if (lane < 32)      { addr = f01 + lane;        thr = T1; }
  else if (lane < 48) { addr = f2 + (lane - 32);  thr = T2; }
  else                { addr = f01;               thr = (int)0x80000000; }
  int guard = 0;
  while (true) {
    int v = __hip_atomic_load(addr, __ATOMIC_RELAXED, __HIP_MEMORY_SCOPE_AGENT);
    if (__all(v >= thr)) break;
    if (++guard > (1 << 26)) break;       // terminate instead of hang on protocol bug
    __builtin_amdgcn_s_sleep(1);
  }
}

__global__ void __launch_bounds__(192, 1)
rnn_persistent(const void* __restrict__ xv,
               const void* __restrict__ Wi2hv,
               const void* __restrict__ biv,
               const void* __restrict__ Whov,
               const void* __restrict__ bov,
               void* __restrict__ outv,
               unsigned short* __restrict__ hbuf,
               int* __restrict__ flags) {
  extern __shared__ unsigned short lds[];
  const int tid = threadIdx.x;
  const int lane = tid & 63;
  const int wave = tid >> 6;     // 0,1: recurrence tiles; 2: output GEMM
  const int blk = blockIdx.x;
  const int c   = blk & 7;       // cluster (batch slice), %8 -> XCD-local heuristic
  const int mem = blk >> 3;      // member 0..15 (hidden/out slice)
  const int b0  = c * 16;
  const int n_base = mem * 32;
  const int o_base = mem * 16;

  // ---- dtype detection: fp32 data read as ushorts has ~25% "huge exponent"
  // patterns in the mantissa halves; genuine bf16 N(0,1) has none.
  bool fp32m;
  {
    const unsigned short* xu = (const unsigned short*)xv;
    int c0 = 0;
    for (int i = lane; i < 4096; i += 64)
      c0 += (((xu[i] >> 7) & 0xFF) >= 0xC0);
    #pragma unroll
    for (int s = 32; s; s >>= 1) c0 += __shfl_xor(c0, s, 64);
    fp32m = (c0 > 100);
  }

  // ---- stage weight slices into LDS (always bf16), 16B-block XOR swizzle ----
  for (int i = tid; i < 32 * 64; i += 192) {              // Wh slice: 32 x 512
    int r = i >> 6, bk = i & 63;
    bf16frag v = load8(Wi2hv, (size_t)(n_base + r) * 768 + 256 + bk * 8, fp32m);
    *reinterpret_cast<bf16frag*>(lds + WH_OFF + r * 512 + ((bk ^ (r & 7)) * 8)) = v;
  }
  for (int i = tid; i < 32 * 32; i += 192) {              // Wx slice: 32 x 256
    int r = i >> 5, bk = i & 31;
    bf16frag v = load8(Wi2hv, (size_t)(n_base + r) * 768 + bk * 8, fp32m);
    *reinterpret_cast<bf16frag*>(lds + WX_OFF + r * 256 + ((bk ^ (r & 7)) * 8)) = v;
  }
  for (int i = tid; i < 16 * 64; i += 192) {              // Who slice: 16 x 512
    int r = i >> 6, bk = i & 63;
    bf16frag v = load8(Whov, (size_t)(o_base + r) * 512 + bk * 8, fp32m);
    *reinterpret_cast<bf16frag*>(lds + WHO_OFF + r * 512 + ((bk ^ (r & 7)) * 8)) = v;
  }
  __syncthreads();

  int* f01 = flags + c * 64;
  int* f2  = f01 + 32;
  const int q  = lane >> 4;
  const int ln = lane & 15;
  float* outf = (float*)outv;
  unsigned short* outh = (unsigned short*)outv;

  if (wave < 2) {
    const int nlB  = wave * 16 + ln;        // local B-frag row in Wh/Wx LDS
    const int n_g  = n_base + nlB;          // global hidden index (bias / store col)
    const float bias = fp32m ? ((const float*)biv)[n_g]
                             : bf2f(((const unsigned short*)biv)[n_g]);
    const int swz = nlB & 7;
    const size_t xrow = (size_t)(b0 + ln) * (S * DI) + q * 8;
    const int flag_idx = mem * 2 + wave;
    const size_t hrow_off = (size_t)(b0 + ln) * DH + q * 8;

    bf16frag xf[8];
    #pragma unroll
    for (int cc = 0; cc < 8; ++cc)
      xf[cc] = load8(xv, xrow + cc * 32, fp32m);

    for (int t = 0; t < S; ++t) {
      f32x4 acc = {bias, bias, bias, bias};
      // x-part: independent of h, runs before the wait (latency hidden in sync)
      #pragma unroll
      for (int cc = 0; cc < 8; ++cc) {
        bf16frag wf = *reinterpret_cast<const bf16frag*>(
            lds + WX_OFF + nlB * 256 + (((cc * 4 + q) ^ swz) * 8));
        acc = __builtin_amdgcn_mfma_f32_16x16x32_bf16(xf[cc], wf, acc, 0, 0, 0);
      }
      if (t + 1 < S) {  // prefetch next step's x; completes during the wait,
                        // so the release vmcnt(0) below never stalls on it
        #pragma unroll
        for (int cc = 0; cc < 8; ++cc)
          xf[cc] = load8(xv, xrow + (size_t)(t + 1) * DI + cc * 32, fp32m);
      }
      if (t > 0) {
        // flags01 >= t : h_{t-1} fully posted. flags2 >= t-3 : wave2 done with
        // h_{t-4} (which hbuf[t&3] is about to overwrite). 4-deep ring => safe.
        cluster_wait(f01, f2, t, t - 3);
        acquire_cc();
        const unsigned short* hsrc = hbuf + (size_t)((t - 1) & 3) * (B * DH) + hrow_off;
        unsigned long long hlo[16], hhi[16];
        #pragma unroll
        for (int cc = 0; cc < 16; ++cc) {
          const unsigned long long* p = reinterpret_cast<const unsigned long long*>(hsrc + cc * 32);
          hlo[cc] = __hip_atomic_load(p,     __ATOMIC_RELAXED, __HIP_MEMORY_SCOPE_AGENT);
          hhi[cc] = __hip_atomic_load(p + 1, __ATOMIC_RELAXED, __HIP_MEMORY_SCOPE_AGENT);
        }
        #pragma unroll
        for (int cc = 0; cc < 16; ++cc) {
          union { unsigned long long u[2]; bf16frag f; } cvt;
          cvt.u[0] = hlo[cc]; cvt.u[1] = hhi[cc];
          bf16frag wf = *reinterpret_cast<const bf16frag*>(
              lds + WH_OFF + nlB * 512 + (((cc * 4 + q) ^ swz) * 8));
          acc = __builtin_amdgcn_mfma_f32_16x16x32_bf16(cvt.f, wf, acc, 0, 0, 0);
        }
      }
      unsigned short* hdst = hbuf + (size_t)(t & 3) * (B * DH);
      #pragma unroll
      for (int r = 0; r < 4; ++r) {
        float hv = fast_tanh(acc[r]);
        unsigned short hu = f2bf(hv);
        // pack col pairs across adjacent lanes -> one coherent 32-bit store
        unsigned int other = __shfl_xor((unsigned int)hu, 1, 64);
        if ((lane & 1) == 0) {
          unsigned int packed = (unsigned int)hu | (other << 16);
          __hip_atomic_store(reinterpret_cast<unsigned int*>(
              hdst + (size_t)(b0 + q * 4 + r) * DH + n_g),
              packed, __ATOMIC_RELAXED, __HIP_MEMORY_SCOPE_AGENT);
        }
        if (t == S - 1) {
          size_t hidx = OUT_MAIN + (size_t)(b0 + q * 4 + r) * DH + n_g;
          if (fp32m) outf[hidx] = hv; else outh[hidx] = hu;   // h_last
        }
      }
      release_vm();  // h stores acked at MALL before flag becomes visible
      if (lane == 0)
        __hip_atomic_store(f01 + flag_idx, t + 1, __ATOMIC_RELAXED, __HIP_MEMORY_SCOPE_AGENT);
    }
  } else {
    // wave2: out_u = h_u @ Who^T + b, trails the recurrence by design
    const int o_g = o_base + ln;
    const float bias = fp32m ? ((const float*)bov)[o_g]
                             : bf2f(((const unsigned short*)bov)[o_g]);
    const int swz = ln & 7;
    const size_t hrow_off = (size_t)(b0 + ln) * DH + q * 8;
    for (int u = 0; u < S; ++u) {
      cluster_wait(f01, f2, u + 1, (int)0x80000000);
      acquire_cc();
      const unsigned short* hsrc = hbuf + (size_t)(u & 3) * (B * DH) + hrow_off;
      unsigned long long hlo[16], hhi[16];
      #pragma unroll
      for (int cc = 0; cc < 16; ++cc) {
        const unsigned long long* p = reinterpret_cast<const unsigned long long*>(hsrc + cc * 32);
        hlo[cc] = __hip_atomic_load(p,     __ATOMIC_RELAXED, __HIP_MEMORY_SCOPE_AGENT);
        hhi[cc] = __hip_atomic_load(p + 1, __ATOMIC_RELAXED, __HIP_MEMORY_SCOPE_AGENT);
      }
      f32x4 acc = {bias, bias, bias, bias};
      #pragma unroll
      for (int cc = 0; cc < 16; ++cc) {
        union { unsigned long long u[2]; bf16frag f; } cvt;
        cvt.u[0] = hlo[cc]; cvt.u[1] = hhi[cc];
        bf16frag wf = *reinterpret_cast<const bf16frag*>(
            lds + WHO_OFF + ln * 512 + (((cc * 4 + q) ^ swz) * 8));
        acc = __builtin_amdgcn_mfma_f32_16x16x32_bf16(cvt.f, wf, acc, 0, 0, 0);
      }
      #pragma unroll
      for (int r = 0; r < 4; ++r) {
        size_t oidx = ((size_t)(b0 + q * 4 + r) * S + u) * DO + o_g;
        if (fp32m) outf[oidx] = acc[r]; else outh[oidx] = f2bf(acc[r]);
      }
      release_vm();  // h_u loads complete before signaling buffer reusable
      if (lane == 0)
        __hip_atomic_store(f2 + mem, u + 1, __ATOMIC_RELAXED, __HIP_MEMORY_SCOPE_AGENT);
    }
  }
}

extern "C" void kernel_launch(void* const* d_in, const int* in_sizes, int n_in,
                              void* d_out, int out_size, void* d_ws, size_t ws_size,
                              hipStream_t stream) {
  const void* x    = d_in[0];
  const void* Wi2h = d_in[1];
  const void* bi   = d_in[2];
  const void* Who  = d_in[3];
  const void* bo   = d_in[4];
  void* out = d_out;
  unsigned short* hbuf = (unsigned short*)d_ws;
  int* flags = (int*)((char*)d_ws + HBUF_BYTES);
  if (ws_size < HBUF_BYTES + FLAGS_BYTES) return;  // loud failure over corruption

  hipMemsetAsync(flags, 0, FLAGS_BYTES, stream);   // monotonic flags start at 0

  void* args[] = { (void*)&x, (void*)&Wi2h, (void*)&bi, (void*)&Who, (void*)&bo,
                   (void*)&out, (void*)&hbuf, (void*)&flags };
  hipError_t e = hipLaunchCooperativeKernel((void*)rnn_persistent, dim3(128), dim3(192),
                                            args, LDS_BYTES, stream);
  if (e != hipSuccess) {
    // co-residency fallback: 128 blocks <= 256 CUs, all resident on dispatch
    rnn_persistent<<<dim3(128), dim3(192), LDS_BYTES, stream>>>(
        x, Wi2h, bi, Who, bo, out, hbuf, flags);
  }
}